// Round 1
// baseline (533.212 us; speedup 1.0000x reference)
//
#include <hip/hip_runtime.h>
#include <math.h>

#define N_NODES 8192
#define F_DIM   2048
#define E_EDGES 262144
#define H1      32
#define H2      16
#define ALPHA_C 0.9f

// ---------------------------------------------------------------------------
// K1: in-degree histogram over dst
__global__ void k_degree(const int* __restrict__ dst, int* __restrict__ deg) {
    int e = blockIdx.x * 256 + threadIdx.x;
    if (e < E_EDGES) atomicAdd(&deg[dst[e]], 1);
}

// ---------------------------------------------------------------------------
// K2: exclusive prefix scan of deg -> rowptr, cursor; norm = rsqrt(max(deg,1))
// single block, 1024 threads, 8 elements each
__global__ void k_scan(const int* __restrict__ deg, int* __restrict__ rowptr,
                       int* __restrict__ cursor, float* __restrict__ norm) {
    __shared__ int sums[1024];
    int t = threadIdx.x;
    int base = t * 8;
    int local[8];
    int s = 0;
#pragma unroll
    for (int i = 0; i < 8; i++) { local[i] = s; s += deg[base + i]; }
    sums[t] = s;
    __syncthreads();
    for (int off = 1; off < 1024; off <<= 1) {
        int v = (t >= off) ? sums[t - off] : 0;
        __syncthreads();
        sums[t] += v;
        __syncthreads();
    }
    int excl = (t == 0) ? 0 : sums[t - 1];
#pragma unroll
    for (int i = 0; i < 8; i++) {
        int r = excl + local[i];
        rowptr[base + i] = r;
        cursor[base + i] = r;
        int d = deg[base + i];
        norm[base + i] = rsqrtf((float)(d > 0 ? d : 1));
    }
    if (t == 1023) rowptr[N_NODES] = sums[1023];
}

// ---------------------------------------------------------------------------
// K3: scatter edges into CSR (counting sort; order within segment irrelevant)
__global__ void k_scatter(const int* __restrict__ src, const int* __restrict__ dst,
                          int* __restrict__ cursor, int* __restrict__ csr_src,
                          int* __restrict__ csr_dst) {
    int e = blockIdx.x * 256 + threadIdx.x;
    if (e < E_EDGES) {
        int d = dst[e];
        int p = atomicAdd(&cursor[d], 1);
        csr_src[p] = src[e];
        csr_dst[p] = d;
    }
}

// ---------------------------------------------------------------------------
// K4: xw = feat @ W0   [8192,2048]@[2048,32], fp32 vector-ALU tiled GEMM.
// BM=128, BN=32, BK=32, 128 threads, TM=8 (rows rt+16m), TN=4 (cols ct+8j).
// split-K = 4 (grid.y), atomicAdd f32 epilogue into zeroed xw.
__global__ __launch_bounds__(128) void k_gemm_xw(const float* __restrict__ feat,
                                                 const float* __restrict__ W0,
                                                 float* __restrict__ xw) {
    __shared__ float As[128][36];  // [row][k], stride 36 -> conflict-free frag reads
    __shared__ float Bt[32][36];   // [col][k] transposed
    const int r0 = blockIdx.x * 128;
    const int kbase = blockIdx.y * 512;
    const int t = threadIdx.x;
    const int ct = t & 7;    // 8 col-threads
    const int rt = t >> 3;   // 16 row-threads
    float acc[8][4] = {};
    for (int kb = 0; kb < 512; kb += 32) {
        __syncthreads();
        // stage A tile: 128 rows x 32 k = 1024 float4, 8 per thread (coalesced)
#pragma unroll
        for (int p = 0; p < 8; p++) {
            int f = t + p * 128;
            int row = f >> 3, q = f & 7;
            float4 v = *(const float4*)&feat[(size_t)(r0 + row) * F_DIM + kbase + kb + q * 4];
            *(float4*)&As[row][q * 4] = v;
        }
        // stage B tile transposed: 32 k x 32 cols
#pragma unroll
        for (int p = 0; p < 2; p++) {
            int f = t + p * 128;
            int k = f >> 3, q = f & 7;
            float4 v = *(const float4*)&W0[(size_t)(kbase + kb + k) * H1 + q * 4];
            Bt[q * 4 + 0][k] = v.x; Bt[q * 4 + 1][k] = v.y;
            Bt[q * 4 + 2][k] = v.z; Bt[q * 4 + 3][k] = v.w;
        }
        __syncthreads();
#pragma unroll
        for (int k4 = 0; k4 < 8; k4++) {
            float4 a[8], b[4];
#pragma unroll
            for (int m = 0; m < 8; m++) a[m] = *(const float4*)&As[rt + 16 * m][k4 * 4];
#pragma unroll
            for (int j = 0; j < 4; j++) b[j] = *(const float4*)&Bt[ct + 8 * j][k4 * 4];
#pragma unroll
            for (int m = 0; m < 8; m++)
#pragma unroll
                for (int j = 0; j < 4; j++)
                    acc[m][j] += a[m].x * b[j].x + a[m].y * b[j].y +
                                 a[m].z * b[j].z + a[m].w * b[j].w;
        }
    }
#pragma unroll
    for (int m = 0; m < 8; m++)
#pragma unroll
        for (int j = 0; j < 4; j++)
            atomicAdd(&xw[(size_t)(r0 + rt + 16 * m) * H1 + ct + 8 * j], acc[m][j]);
}

// ---------------------------------------------------------------------------
// K5: first graph conv aggregate: h[n] = relu(norm[n] * sum_{s->n} norm[s]*xw[s])
// one wave per node; lanes 0..31 / 32..63 process alternating edges
__global__ void k_agg1(const int* __restrict__ rowptr, const int* __restrict__ csr_src,
                       const float* __restrict__ xw, const float* __restrict__ norm,
                       float* __restrict__ h) {
    int wid = (blockIdx.x * blockDim.x + threadIdx.x) >> 6;  // node id (wave-uniform)
    if (wid >= N_NODES) return;
    int lane = threadIdx.x & 63;
    int col = lane & 31, half = lane >> 5;
    int beg = rowptr[wid], end = rowptr[wid + 1];
    float acc = 0.0f;
    for (int p = beg + half; p < end; p += 2) {
        int s = csr_src[p];
        acc += norm[s] * xw[(size_t)s * H1 + col];
    }
    acc += __shfl_xor(acc, 32, 64);
    if (half == 0) {
        float v = norm[wid] * acc;
        h[(size_t)wid * H1 + col] = fmaxf(v, 0.0f);
    }
}

// ---------------------------------------------------------------------------
// K6: per-node small math: hm[n] = norm[n]*(h[n]@Wm); dd/ds = gate dots
__global__ void k_node_small(const float* __restrict__ h, const float* __restrict__ Wm,
                             const float* __restrict__ gw, const float* __restrict__ norm,
                             float* __restrict__ hm, float* __restrict__ dd,
                             float* __restrict__ ds) {
    int n = blockIdx.x * blockDim.x + threadIdx.x;
    if (n >= N_NODES) return;
    float hv[H1];
#pragma unroll
    for (int c = 0; c < H1; c++) hv[c] = h[(size_t)n * H1 + c];
    float nn = norm[n];
#pragma unroll
    for (int j = 0; j < H2; j++) {
        float s = 0.0f;
#pragma unroll
        for (int c = 0; c < H1; c++) s += hv[c] * Wm[c * H2 + j];
        hm[(size_t)n * H2 + j] = nn * s;
    }
    float a = 0.0f, b = 0.0f;
#pragma unroll
    for (int c = 0; c < H1; c++) {
        a += hv[c] * gw[c];        // h_dst part (first 32 of gate_w)
        b += hv[c] * gw[H1 + c];   // h_src part
    }
    dd[n] = a;
    ds[n] = b;
}

// ---------------------------------------------------------------------------
// K6.5: per-edge gate coefficient (CSR order)
__global__ void k_coef(const int* __restrict__ csr_src, const int* __restrict__ csr_dst,
                       const float* __restrict__ dd, const float* __restrict__ ds,
                       const float* __restrict__ norm, const float* __restrict__ gb,
                       float* __restrict__ coef) {
    int p = blockIdx.x * 256 + threadIdx.x;
    if (p < E_EDGES) {
        int s = csr_src[p], d = csr_dst[p];
        float g = tanhf(dd[d] + ds[s] + gb[0]);
        coef[p] = g * norm[d] * norm[s] * ALPHA_C;
    }
}

// ---------------------------------------------------------------------------
// K7: fused second aggregation: z_auto[n][0:32] and mean[n][0:16]
// one wave per node; lanes 0..31 -> z_auto cols, lanes 32..47 -> mean cols
__global__ void k_agg2(const int* __restrict__ rowptr, const int* __restrict__ csr_src,
                       const float* __restrict__ coef, const float* __restrict__ h,
                       const float* __restrict__ hm, const float* __restrict__ norm,
                       float* __restrict__ z_auto, float* __restrict__ mean) {
    int wid = (blockIdx.x * blockDim.x + threadIdx.x) >> 6;
    if (wid >= N_NODES) return;
    int lane = threadIdx.x & 63;
    int col = lane & 31;
    bool isZ = lane < 32;
    bool isM = (lane >= 32) && (lane < 48);
    int beg = rowptr[wid], end = rowptr[wid + 1];
    float acc = 0.0f;
    for (int p = beg; p < end; p++) {
        int s = csr_src[p];
        float cf = coef[p];
        size_t offv = isZ ? ((size_t)s * H1 + col) : ((size_t)s * H2 + (lane & 15));
        const float* bp = isZ ? h : hm;
        float v = bp[offv];
        acc += isZ ? v * cf : (isM ? v : 0.0f);
    }
    if (isZ) z_auto[(size_t)wid * H1 + col] = acc;
    else if (isM) mean[(size_t)wid * H2 + (lane & 15)] = norm[wid] * acc;
}

// ---------------------------------------------------------------------------
// K8: logstd = (z_auto + alpha*h) @ t2_w ; z = noise*exp(logstd) + mean
__global__ void k_z(const float* __restrict__ z_auto, const float* __restrict__ h,
                    const float* __restrict__ t2, const float* __restrict__ noise,
                    const float* __restrict__ mean, float* __restrict__ z) {
    int gid = blockIdx.x * 256 + threadIdx.x;
    if (gid >= N_NODES * H2) return;
    int n = gid >> 4, k = gid & 15;
    float v = 0.0f;
#pragma unroll
    for (int c = 0; c < H1; c++)
        v += (z_auto[(size_t)n * H1 + c] + ALPHA_C * h[(size_t)n * H1 + c]) * t2[c * H2 + k];
    z[gid] = noise[gid] * __expf(v) + mean[gid];
}

// ---------------------------------------------------------------------------
// K9: out = sigmoid(z @ z^T), 128x128 tile per block, 8x8 per thread.
// Fragment mapping: rows ty*4+{0..3} and 64+ty*4+{0..3}; cols tx*4 / 64+tx*4
// -> LDS fragment reads are broadcast (a) or 2-way (b) = free; stores coalesced.
__global__ __launch_bounds__(256) void k_outer(const float* __restrict__ z,
                                               float* __restrict__ out) {
    __shared__ float Zr[H2][128];
    __shared__ float Zc[H2][128];
    const int bx = blockIdx.x, by = blockIdx.y;
    const int t = threadIdx.x;
    // stage both tiles transposed into LDS (coalesced global f4 loads)
#pragma unroll
    for (int p = 0; p < 2; p++) {
        int fi = t + p * 256;
        int row = fi >> 2, q = fi & 3;
        float4 v = *(const float4*)&z[(size_t)(by * 128 + row) * H2 + q * 4];
        Zr[q * 4 + 0][row] = v.x; Zr[q * 4 + 1][row] = v.y;
        Zr[q * 4 + 2][row] = v.z; Zr[q * 4 + 3][row] = v.w;
        float4 w = *(const float4*)&z[(size_t)(bx * 128 + row) * H2 + q * 4];
        Zc[q * 4 + 0][row] = w.x; Zc[q * 4 + 1][row] = w.y;
        Zc[q * 4 + 2][row] = w.z; Zc[q * 4 + 3][row] = w.w;
    }
    __syncthreads();
    const int tx = t & 15, ty = t >> 4;
    float acc[8][8] = {};
#pragma unroll
    for (int k = 0; k < H2; k++) {
        float a[8], b[8];
        *(float4*)&a[0] = *(const float4*)&Zr[k][ty * 4];
        *(float4*)&a[4] = *(const float4*)&Zr[k][64 + ty * 4];
        *(float4*)&b[0] = *(const float4*)&Zc[k][tx * 4];
        *(float4*)&b[4] = *(const float4*)&Zc[k][64 + tx * 4];
#pragma unroll
        for (int i = 0; i < 8; i++)
#pragma unroll
            for (int j = 0; j < 8; j++) acc[i][j] += a[i] * b[j];
    }
#pragma unroll
    for (int i = 0; i < 8; i++) {
        size_t row = (size_t)by * 128 + ((i < 4) ? (ty * 4 + i) : (64 + ty * 4 + i - 4));
        float4 o0, o1;
        o0.x = 1.0f / (1.0f + __expf(-acc[i][0]));
        o0.y = 1.0f / (1.0f + __expf(-acc[i][1]));
        o0.z = 1.0f / (1.0f + __expf(-acc[i][2]));
        o0.w = 1.0f / (1.0f + __expf(-acc[i][3]));
        o1.x = 1.0f / (1.0f + __expf(-acc[i][4]));
        o1.y = 1.0f / (1.0f + __expf(-acc[i][5]));
        o1.z = 1.0f / (1.0f + __expf(-acc[i][6]));
        o1.w = 1.0f / (1.0f + __expf(-acc[i][7]));
        *(float4*)&out[row * N_NODES + bx * 128 + tx * 4] = o0;
        *(float4*)&out[row * N_NODES + bx * 128 + 64 + tx * 4] = o1;
    }
}

// ---------------------------------------------------------------------------
extern "C" void kernel_launch(void* const* d_in, const int* in_sizes, int n_in,
                              void* d_out, int out_size, void* d_ws, size_t ws_size,
                              hipStream_t stream) {
    const float* feat  = (const float*)d_in[0];
    const float* W0    = (const float*)d_in[1];
    const float* Wm    = (const float*)d_in[2];
    const float* gw    = (const float*)d_in[3];
    const float* gb    = (const float*)d_in[4];
    const float* t2    = (const float*)d_in[5];
    const float* noise = (const float*)d_in[6];
    const int*   src   = (const int*)d_in[7];
    const int*   dst   = (const int*)d_in[8];
    float* out = (float*)d_out;

    char* w = (char*)d_ws;
    size_t off = 0;
    auto alloc = [&](size_t bytes) {
        void* p = w + off;
        off = (off + bytes + 255) & ~(size_t)255;
        return p;
    };
    int*   deg     = (int*)alloc(N_NODES * 4);
    int*   rowptr  = (int*)alloc((N_NODES + 1) * 4);
    int*   cursor  = (int*)alloc(N_NODES * 4);
    int*   csr_src = (int*)alloc(E_EDGES * 4);
    int*   csr_dst = (int*)alloc(E_EDGES * 4);
    float* norm    = (float*)alloc(N_NODES * 4);
    float* xw      = (float*)alloc((size_t)N_NODES * H1 * 4);
    float* h       = (float*)alloc((size_t)N_NODES * H1 * 4);
    float* hm      = (float*)alloc((size_t)N_NODES * H2 * 4);
    float* dd      = (float*)alloc(N_NODES * 4);
    float* ds      = (float*)alloc(N_NODES * 4);
    float* coef    = (float*)alloc(E_EDGES * 4);
    float* z_auto  = (float*)alloc((size_t)N_NODES * H1 * 4);
    float* mean    = (float*)alloc((size_t)N_NODES * H2 * 4);
    float* z       = (float*)alloc((size_t)N_NODES * H2 * 4);

    hipMemsetAsync(deg, 0, N_NODES * 4, stream);
    hipMemsetAsync(xw, 0, (size_t)N_NODES * H1 * 4, stream);

    k_degree<<<E_EDGES / 256, 256, 0, stream>>>(dst, deg);
    k_scan<<<1, 1024, 0, stream>>>(deg, rowptr, cursor, norm);
    k_scatter<<<E_EDGES / 256, 256, 0, stream>>>(src, dst, cursor, csr_src, csr_dst);
    k_gemm_xw<<<dim3(N_NODES / 128, 4), 128, 0, stream>>>(feat, W0, xw);
    k_agg1<<<N_NODES / 4, 256, 0, stream>>>(rowptr, csr_src, xw, norm, h);
    k_node_small<<<N_NODES / 256, 256, 0, stream>>>(h, Wm, gw, norm, hm, dd, ds);
    k_coef<<<E_EDGES / 256, 256, 0, stream>>>(csr_src, csr_dst, dd, ds, norm, gb, coef);
    k_agg2<<<N_NODES / 4, 256, 0, stream>>>(rowptr, csr_src, coef, h, hm, norm, z_auto, mean);
    k_z<<<(N_NODES * H2) / 256, 256, 0, stream>>>(z_auto, h, t2, noise, mean, z);
    k_outer<<<dim3(N_NODES / 128, N_NODES / 128), 256, 0, stream>>>(z, out);
}

// Round 3
// 452.485 us; speedup vs baseline: 1.1784x; 1.1784x over previous
//
#include <hip/hip_runtime.h>
#include <math.h>

#define N_NODES 8192
#define F_DIM   2048
#define E_EDGES 262144
#define H1      32
#define H2      16
#define ALPHA_C 0.9f

typedef float f4v __attribute__((ext_vector_type(4)));

// ---------------------------------------------------------------------------
// K1: in-degree histogram over dst
__global__ void k_degree(const int* __restrict__ dst, int* __restrict__ deg) {
    int e = blockIdx.x * 256 + threadIdx.x;
    if (e < E_EDGES) atomicAdd(&deg[dst[e]], 1);
}

// ---------------------------------------------------------------------------
// K2: exclusive prefix scan of deg -> rowptr, cursor; norm = rsqrt(max(deg,1))
__global__ void k_scan(const int* __restrict__ deg, int* __restrict__ rowptr,
                       int* __restrict__ cursor, float* __restrict__ norm) {
    __shared__ int sums[1024];
    int t = threadIdx.x;
    int base = t * 8;
    int local[8];
    int s = 0;
#pragma unroll
    for (int i = 0; i < 8; i++) { local[i] = s; s += deg[base + i]; }
    sums[t] = s;
    __syncthreads();
    for (int off = 1; off < 1024; off <<= 1) {
        int v = (t >= off) ? sums[t - off] : 0;
        __syncthreads();
        sums[t] += v;
        __syncthreads();
    }
    int excl = (t == 0) ? 0 : sums[t - 1];
#pragma unroll
    for (int i = 0; i < 8; i++) {
        int r = excl + local[i];
        rowptr[base + i] = r;
        cursor[base + i] = r;
        int d = deg[base + i];
        norm[base + i] = rsqrtf((float)(d > 0 ? d : 1));
    }
    if (t == 1023) rowptr[N_NODES] = sums[1023];
}

// ---------------------------------------------------------------------------
// K3: scatter edges into CSR (counting sort; order within segment irrelevant)
__global__ void k_scatter(const int* __restrict__ src, const int* __restrict__ dst,
                          int* __restrict__ cursor, int* __restrict__ csr_src) {
    int e = blockIdx.x * 256 + threadIdx.x;
    if (e < E_EDGES) {
        int d = dst[e];
        int p = atomicAdd(&cursor[d], 1);
        csr_src[p] = src[e];
    }
}

// ---------------------------------------------------------------------------
// K4: xw = feat @ W0   [8192,2048]@[2048,32], fp32 vector-ALU tiled GEMM.
// BM=128, BN=32, BK=32, 256 threads, TM=4 (rows rt+32m), TN=4 (cols ct+8j).
// split-K = 16 (grid.y, 128 K each) -> 1024 blocks, good occupancy.
// Fragment LDS reads: conflict-free broadcast (stride-36 rows).
__global__ __launch_bounds__(256) void k_gemm_xw(const float* __restrict__ feat,
                                                 const float* __restrict__ W0,
                                                 float* __restrict__ xw) {
    __shared__ float As[128][36];
    __shared__ float Bt[32][36];
    const int r0 = blockIdx.x * 128;
    const int kbase = blockIdx.y * 128;
    const int t = threadIdx.x;
    const int ct = t & 7;    // 8 col-threads  (cols ct + 8j)
    const int rt = t >> 3;   // 32 row-threads (rows rt + 32m)
    float acc[4][4] = {};
    for (int kb = 0; kb < 128; kb += 32) {
        const int koff = kbase + kb;
        __syncthreads();
        // stage A tile: 128 rows x 32 k = 1024 float4, 4 per thread (coalesced)
#pragma unroll
        for (int p = 0; p < 4; p++) {
            int f = t + p * 256;
            int row = f >> 3, q = f & 7;
            float4 v = *(const float4*)&feat[(size_t)(r0 + row) * F_DIM + koff + q * 4];
            *(float4*)&As[row][q * 4] = v;
        }
        // stage B tile transposed: 32 k x 32 cols, 1 float4 per thread
        {
            int k = t >> 3, q = t & 7;
            float4 v = *(const float4*)&W0[(size_t)(koff + k) * H1 + q * 4];
            Bt[q * 4 + 0][k] = v.x; Bt[q * 4 + 1][k] = v.y;
            Bt[q * 4 + 2][k] = v.z; Bt[q * 4 + 3][k] = v.w;
        }
        __syncthreads();
#pragma unroll
        for (int k4 = 0; k4 < 8; k4++) {
            float4 a[4], b[4];
#pragma unroll
            for (int m = 0; m < 4; m++) a[m] = *(const float4*)&As[rt + 32 * m][k4 * 4];
#pragma unroll
            for (int j = 0; j < 4; j++) b[j] = *(const float4*)&Bt[ct + 8 * j][k4 * 4];
#pragma unroll
            for (int m = 0; m < 4; m++)
#pragma unroll
                for (int j = 0; j < 4; j++)
                    acc[m][j] += a[m].x * b[j].x + a[m].y * b[j].y +
                                 a[m].z * b[j].z + a[m].w * b[j].w;
        }
    }
#pragma unroll
    for (int m = 0; m < 4; m++)
#pragma unroll
        for (int j = 0; j < 4; j++)
            atomicAdd(&xw[(size_t)(r0 + rt + 32 * m) * H1 + ct + 8 * j], acc[m][j]);
}

// ---------------------------------------------------------------------------
// K5: first graph conv aggregate: h[n] = relu(norm[n] * sum_{s->n} norm[s]*xw[s])
// one wave per node; lanes 0..31 / 32..63 process alternating edges
__global__ void k_agg1(const int* __restrict__ rowptr, const int* __restrict__ csr_src,
                       const float* __restrict__ xw, const float* __restrict__ norm,
                       float* __restrict__ h) {
    int wid = (blockIdx.x * blockDim.x + threadIdx.x) >> 6;  // node id (wave-uniform)
    if (wid >= N_NODES) return;
    int lane = threadIdx.x & 63;
    int col = lane & 31, half = lane >> 5;
    int beg = rowptr[wid], end = rowptr[wid + 1];
    float acc = 0.0f;
    for (int p = beg + half; p < end; p += 2) {
        int s = csr_src[p];
        acc += norm[s] * xw[(size_t)s * H1 + col];
    }
    acc += __shfl_xor(acc, 32, 64);
    if (half == 0) {
        float v = norm[wid] * acc;
        h[(size_t)wid * H1 + col] = fmaxf(v, 0.0f);
    }
}

// ---------------------------------------------------------------------------
// K6: per-node small math: hm[n] = norm[n]*(h[n]@Wm); dd/ds = gate dots
__global__ void k_node_small(const float* __restrict__ h, const float* __restrict__ Wm,
                             const float* __restrict__ gw, const float* __restrict__ norm,
                             float* __restrict__ hm, float* __restrict__ dd,
                             float* __restrict__ ds) {
    int n = blockIdx.x * blockDim.x + threadIdx.x;
    if (n >= N_NODES) return;
    float hv[H1];
#pragma unroll
    for (int c = 0; c < H1; c++) hv[c] = h[(size_t)n * H1 + c];
    float nn = norm[n];
#pragma unroll
    for (int j = 0; j < H2; j++) {
        float s = 0.0f;
#pragma unroll
        for (int c = 0; c < H1; c++) s += hv[c] * Wm[c * H2 + j];
        hm[(size_t)n * H2 + j] = nn * s;
    }
    float a = 0.0f, b = 0.0f;
#pragma unroll
    for (int c = 0; c < H1; c++) {
        a += hv[c] * gw[c];        // h_dst part (first 32 of gate_w)
        b += hv[c] * gw[H1 + c];   // h_src part
    }
    dd[n] = a;
    ds[n] = b;
}

// ---------------------------------------------------------------------------
// K7 (fused): per-node edge-gated aggregation + mean + logstd + reparameterize.
// One wave per node n:
//   lanes 0..31:  acc_z[col] = sum coef*h[s][col], coef wave-uniform per edge
//   lanes 32..47: acc_m[k]  = sum hm[s][k]        (mean = norm[n]*acc_m)
// Then t[c] = acc_z + alpha*h[n][c] -> LDS; lanes 32..47 compute
// logstd[k] = sum_c t[c]*t2[c][k];  z = noise*exp(logstd) + mean.
__global__ __launch_bounds__(256) void k_agg2z(const int* __restrict__ rowptr,
                                               const int* __restrict__ csr_src,
                                               const float* __restrict__ h,
                                               const float* __restrict__ hm,
                                               const float* __restrict__ dd,
                                               const float* __restrict__ ds,
                                               const float* __restrict__ norm,
                                               const float* __restrict__ gb,
                                               const float* __restrict__ t2,
                                               const float* __restrict__ noise,
                                               float* __restrict__ z) {
    __shared__ float sh[4][H1];  // one 32-float row per wave
    int wid = (blockIdx.x * blockDim.x + threadIdx.x) >> 6;  // node id
    int w = (threadIdx.x >> 6) & 3;                          // wave in block
    int lane = threadIdx.x & 63;
    int col = lane & 31;
    int beg = rowptr[wid], end = rowptr[wid + 1];
    float dd_n = dd[wid];
    float norm_n = norm[wid];
    float gb0 = gb[0];
    bool isZ = lane < 32;
    bool isM = (lane >= 32) && (lane < 48);
    float acc = 0.0f;
    for (int p = beg; p < end; p++) {
        int s = csr_src[p];
        float cf = tanhf(dd_n + ds[s] + gb0) * norm_n * norm[s] * ALPHA_C;
        size_t offv = isZ ? ((size_t)s * H1 + col) : ((size_t)s * H2 + (lane & 15));
        float v = (isZ || isM) ? (isZ ? h : hm)[offv] : 0.0f;
        acc += isZ ? (v * cf) : v;
    }
    if (isZ) sh[w][col] = acc + ALPHA_C * h[(size_t)wid * H1 + col];
    __syncthreads();
    if (isM) {
        int k = lane & 15;
        float ls = 0.0f;
#pragma unroll
        for (int c = 0; c < H1; c++) ls += sh[w][c] * t2[c * H2 + k];
        size_t zi = (size_t)wid * H2 + k;
        z[zi] = noise[zi] * __expf(ls) + norm_n * acc;
    }
}

// ---------------------------------------------------------------------------
// K8: out = sigmoid(z @ z^T), 128x128 tile per block, 8x8 per thread.
// a-frag reads broadcast, b-frag 2-way (free); non-temporal coalesced stores.
__global__ __launch_bounds__(256) void k_outer(const float* __restrict__ z,
                                               float* __restrict__ out) {
    __shared__ float Zr[H2][128];
    __shared__ float Zc[H2][128];
    const int bx = blockIdx.x, by = blockIdx.y;
    const int t = threadIdx.x;
#pragma unroll
    for (int p = 0; p < 2; p++) {
        int fi = t + p * 256;
        int row = fi >> 2, q = fi & 3;
        float4 v = *(const float4*)&z[(size_t)(by * 128 + row) * H2 + q * 4];
        Zr[q * 4 + 0][row] = v.x; Zr[q * 4 + 1][row] = v.y;
        Zr[q * 4 + 2][row] = v.z; Zr[q * 4 + 3][row] = v.w;
        float4 w = *(const float4*)&z[(size_t)(bx * 128 + row) * H2 + q * 4];
        Zc[q * 4 + 0][row] = w.x; Zc[q * 4 + 1][row] = w.y;
        Zc[q * 4 + 2][row] = w.z; Zc[q * 4 + 3][row] = w.w;
    }
    __syncthreads();
    const int tx = t & 15, ty = t >> 4;
    float acc[8][8] = {};
#pragma unroll
    for (int k = 0; k < H2; k++) {
        float a[8], b[8];
        *(float4*)&a[0] = *(const float4*)&Zr[k][ty * 4];
        *(float4*)&a[4] = *(const float4*)&Zr[k][64 + ty * 4];
        *(float4*)&b[0] = *(const float4*)&Zc[k][tx * 4];
        *(float4*)&b[4] = *(const float4*)&Zc[k][64 + tx * 4];
#pragma unroll
        for (int i = 0; i < 8; i++)
#pragma unroll
            for (int j = 0; j < 8; j++) acc[i][j] += a[i] * b[j];
    }
#pragma unroll
    for (int i = 0; i < 8; i++) {
        size_t row = (size_t)by * 128 + ((i < 4) ? (ty * 4 + i) : (64 + ty * 4 + i - 4));
        f4v o0, o1;
        o0.x = 1.0f / (1.0f + __expf(-acc[i][0]));
        o0.y = 1.0f / (1.0f + __expf(-acc[i][1]));
        o0.z = 1.0f / (1.0f + __expf(-acc[i][2]));
        o0.w = 1.0f / (1.0f + __expf(-acc[i][3]));
        o1.x = 1.0f / (1.0f + __expf(-acc[i][4]));
        o1.y = 1.0f / (1.0f + __expf(-acc[i][5]));
        o1.z = 1.0f / (1.0f + __expf(-acc[i][6]));
        o1.w = 1.0f / (1.0f + __expf(-acc[i][7]));
        __builtin_nontemporal_store(o0, (f4v*)&out[row * N_NODES + bx * 128 + tx * 4]);
        __builtin_nontemporal_store(o1, (f4v*)&out[row * N_NODES + bx * 128 + 64 + tx * 4]);
    }
}

// ---------------------------------------------------------------------------
extern "C" void kernel_launch(void* const* d_in, const int* in_sizes, int n_in,
                              void* d_out, int out_size, void* d_ws, size_t ws_size,
                              hipStream_t stream) {
    const float* feat  = (const float*)d_in[0];
    const float* W0    = (const float*)d_in[1];
    const float* Wm    = (const float*)d_in[2];
    const float* gw    = (const float*)d_in[3];
    const float* gb    = (const float*)d_in[4];
    const float* t2    = (const float*)d_in[5];
    const float* noise = (const float*)d_in[6];
    const int*   src   = (const int*)d_in[7];
    const int*   dst   = (const int*)d_in[8];
    float* out = (float*)d_out;

    char* w = (char*)d_ws;
    size_t off = 0;
    auto alloc = [&](size_t bytes) {
        void* p = w + off;
        off = (off + bytes + 255) & ~(size_t)255;
        return p;
    };
    // deg and xw first + contiguous -> single zeroing memset
    int*   deg     = (int*)alloc(N_NODES * 4);
    float* xw      = (float*)alloc((size_t)N_NODES * H1 * 4);
    size_t zero_bytes = off;
    int*   rowptr  = (int*)alloc((N_NODES + 1) * 4);
    int*   cursor  = (int*)alloc(N_NODES * 4);
    int*   csr_src = (int*)alloc(E_EDGES * 4);
    float* norm    = (float*)alloc(N_NODES * 4);
    float* h       = (float*)alloc((size_t)N_NODES * H1 * 4);
    float* hm      = (float*)alloc((size_t)N_NODES * H2 * 4);
    float* dd      = (float*)alloc(N_NODES * 4);
    float* ds      = (float*)alloc(N_NODES * 4);
    float* z       = (float*)alloc((size_t)N_NODES * H2 * 4);

    (void)hipMemsetAsync(deg, 0, zero_bytes, stream);

    k_degree<<<E_EDGES / 256, 256, 0, stream>>>(dst, deg);
    k_scan<<<1, 1024, 0, stream>>>(deg, rowptr, cursor, norm);
    k_scatter<<<E_EDGES / 256, 256, 0, stream>>>(src, dst, cursor, csr_src);
    k_gemm_xw<<<dim3(N_NODES / 128, 16), 256, 0, stream>>>(feat, W0, xw);
    k_agg1<<<N_NODES / 4, 256, 0, stream>>>(rowptr, csr_src, xw, norm, h);
    k_node_small<<<N_NODES / 256, 256, 0, stream>>>(h, Wm, gw, norm, hm, dd, ds);
    k_agg2z<<<N_NODES / 4, 256, 0, stream>>>(rowptr, csr_src, h, hm, dd, ds, norm,
                                             gb, t2, noise, z);
    k_outer<<<dim3(N_NODES / 128, N_NODES / 128), 256, 0, stream>>>(z, out);
}